// Round 15
// baseline (274.763 us; speedup 1.0000x reference)
//
#include <hip/hip_runtime.h>

#define D 128
#define BTILE 4096      // items per bucket block (16/thread)
#define BCAP 12288      // fixed per-bucket staging capacity (mean ~5-6.4k, sigma ~80)

typedef __bf16 bf16;
typedef __attribute__((ext_vector_type(4))) __bf16 bf16x4;
typedef __attribute__((ext_vector_type(8))) __bf16 bf16x8;
typedef __attribute__((ext_vector_type(4))) float f32x4;
typedef __attribute__((ext_vector_type(2))) float f32x2;

__device__ __forceinline__ int pick4(int4 v, int r) {
    return r == 0 ? v.x : r == 1 ? v.y : r == 2 ? v.z : v.w;
}

// ---------------- fp8 e4m3 helpers (HW cvt if available, bit-op fallback) ----------------
#if defined(__has_builtin)
#  if __has_builtin(__builtin_amdgcn_cvt_pk_f32_fp8) && __has_builtin(__builtin_amdgcn_cvt_pk_fp8_f32)
#    define HWFP8 1
#  endif
#endif
#ifndef HWFP8
#  define HWFP8 0
#endif

__device__ __forceinline__ void dec_fp8x8(uint2 p, float* o) {
#if HWFP8
    f32x2 a = __builtin_amdgcn_cvt_pk_f32_fp8((int)p.x, false);
    f32x2 b = __builtin_amdgcn_cvt_pk_f32_fp8((int)p.x, true);
    f32x2 c = __builtin_amdgcn_cvt_pk_f32_fp8((int)p.y, false);
    f32x2 d = __builtin_amdgcn_cvt_pk_f32_fp8((int)p.y, true);
    o[0]=a.x; o[1]=a.y; o[2]=b.x; o[3]=b.y; o[4]=c.x; o[5]=c.y; o[6]=d.x; o[7]=d.y;
#else
    unsigned w0 = p.x, w1 = p.y;
#pragma unroll
    for (int k = 0; k < 8; ++k) {
        unsigned b8 = ((k < 4 ? w0 : w1) >> ((k & 3) * 8)) & 0xffu;
        unsigned bits = ((b8 & 0x80u) << 24) | ((b8 & 0x7fu) << 20);
        o[k] = __uint_as_float(bits) * 0x1p+120f;
    }
#endif
}

#if !HWFP8
__device__ __forceinline__ unsigned enc_fp8_sw(float x) {
    unsigned u = __float_as_uint(x);
    unsigned s = (u >> 24) & 0x80u;
    int e = (int)((u >> 23) & 0xffu) - 127;
    unsigned m = u & 0x7fffffu;
    if (e < -6) return s;
    unsigned mant = m >> 20;
    unsigned rest = m & 0xfffffu;
    mant += (rest > 0x80000u) || (rest == 0x80000u && (mant & 1u));
    unsigned E = (unsigned)(e + 7);
    if (mant == 8u) { mant = 0u; E += 1u; }
    if (E > 15u || (E == 15u && mant > 6u)) return s | 0x7eu;
    return s | (E << 3) | mant;
}
#endif

__device__ __forceinline__ uint2 enc_fp8x8(const float* v) {
#if HWFP8
    int lo = 0, hi = 0;
    lo = __builtin_amdgcn_cvt_pk_fp8_f32(v[0], v[1], lo, false);
    lo = __builtin_amdgcn_cvt_pk_fp8_f32(v[2], v[3], lo, true);
    hi = __builtin_amdgcn_cvt_pk_fp8_f32(v[4], v[5], hi, false);
    hi = __builtin_amdgcn_cvt_pk_fp8_f32(v[6], v[7], hi, true);
    return make_uint2((unsigned)lo, (unsigned)hi);
#else
    unsigned w0 = 0, w1 = 0;
#pragma unroll
    for (int k = 0; k < 4; ++k) w0 |= enc_fp8_sw(v[k]) << (k * 8);
#pragma unroll
    for (int k = 0; k < 4; ++k) w1 |= enc_fp8_sw(v[4 + k]) << (k * 8);
    return make_uint2(w0, w1);
#endif
}

__device__ __forceinline__ unsigned char enc_fp8_1(float x) {
#if HWFP8
    int v = __builtin_amdgcn_cvt_pk_fp8_f32(x, 0.0f, 0, false);
    return (unsigned char)(v & 0xff);
#else
    return (unsigned char)enc_fp8_sw(x);
#endif
}

// byte-addressed row load; F8: 8B/lane fp8 -> 8 floats, else 16B/lane bf16 -> 8 floats
template<int F8>
__device__ __forceinline__ void row_load(const unsigned char* src, int g, int rs, int of,
                                         int lc, float* o) {
    if constexpr (F8) {
        uint2 p = *(const uint2*)(src + (size_t)g * rs + of + lc * 8);
        dec_fp8x8(p, o);
    } else {
        bf16x8 p = *(const bf16x8*)(src + (size_t)g * rs + of + lc * 16);
#pragma unroll
        for (int k = 0; k < 8; ++k) o[k] = (float)p[k];
    }
}

// ---------------- fused prep: fp8(vfeat), bf16(efeat), weight folds ----------------------
__global__ __launch_bounds__(256) void prep_all(
    const float* __restrict__ vfeat, int n8v, unsigned char* __restrict__ nP8, int rs8,
    const float* __restrict__ efeat, int n4e, bf16* __restrict__ mE,
    const float* __restrict__ Wv, const float* __restrict__ W1, const float* __restrict__ b1,
    const float* __restrict__ We, const float* __restrict__ W2, const float* __restrict__ b2,
    float* __restrict__ W1f, float* __restrict__ b1f,
    float* __restrict__ W2f, float* __restrict__ b2f,
    int nb8, int nb16)
{
    const int b = blockIdx.x, t = threadIdx.x;
    if (b < nb8) {
        int i = b * 256 + t;
        if (i >= n8v) return;
        float4 f0 = *(const float4*)(vfeat + (size_t)i * 8);
        float4 f1 = *(const float4*)(vfeat + (size_t)i * 8 + 4);
        float v[8] = { f0.x, f0.y, f0.z, f0.w, f1.x, f1.y, f1.z, f1.w };
        int row = i >> 4, lane = i & 15;
        *(uint2*)(nP8 + (size_t)row * rs8 + lane * 8) = enc_fp8x8(v);
    } else if (b < nb8 + nb16) {
        int i = (b - nb8) * 256 + t;
        if (i >= n4e) return;
        float4 f = ((const float4*)efeat)[i];
        bf16x4 v = { (bf16)f.x, (bf16)f.y, (bf16)f.z, (bf16)f.w };
        ((bf16x4*)mE)[i] = v;
    } else {
        int gid = (b - nb8 - nb16) * 256 + t;
        if (gid < 65536) {
            int which = gid >> 15;
            int i = (gid >> 8) & 127;
            int j = gid & 255;
            const float* A = which ? We : Wv;
            const float* B = which ? W2 : W1;
            float s = 0.0f;
            for (int k = 0; k < 128; ++k) s += A[i * 128 + k] * B[k * 256 + j];
            (which ? W2f : W1f)[i * 256 + j] = s;
        } else if (gid < 65536 + 256) {
            int tt = gid - 65536, which = tt >> 7, i = tt & 127;
            const float* A = which ? We : Wv;
            const float* B = which ? b2 : b1;
            float s = 0.0f;
            for (int k = 0; k < 128; ++k) s += A[i * 128 + k] * B[k];
            (which ? b2f : b1f)[i] = s;
        }
    }
}

// ---------------- DUAL MFMA GEMM (K=128): o1 = fp8(X@W1^T * s1), o2 = bf16(X@W2^T) -------
__global__ __launch_bounds__(256) void gemm_dual(
    const bf16* __restrict__ X, const float* __restrict__ W1, const float* __restrict__ W2,
    unsigned char* __restrict__ o1, float s1, bf16* __restrict__ o2, int R)
{
    __shared__ __align__(16) bf16 Ws[2][D * D];   // 64 KB
    const int t = threadIdx.x;
    for (int g = t; g < D * 16; g += 256) {
        int row = g >> 4, blk = g & 15;
        int sb = (blk ^ (row & 15)) * 8;
#pragma unroll
        for (int wsel = 0; wsel < 2; ++wsel) {
            const float* src = (wsel ? W2 : W1) + (size_t)row * D + blk * 8;
            float4 f0 = *(const float4*)(src);
            float4 f1 = *(const float4*)(src + 4);
            bf16x8 v = { (bf16)f0.x, (bf16)f0.y, (bf16)f0.z, (bf16)f0.w,
                         (bf16)f1.x, (bf16)f1.y, (bf16)f1.z, (bf16)f1.w };
            *(bf16x8*)(&Ws[wsel][row * D + sb]) = v;
        }
    }
    __syncthreads();

    const int lane = t & 63, wave = t >> 6;
    const int lrow = lane & 15, lk8 = lane >> 4;
    const int r0 = blockIdx.x * 128 + wave * 32;

    f32x4 acc[2][2][8] = {};   // [wsel][mf][nf]
    for (int ks = 0; ks < 4; ++ks) {
        bf16x8 a[2];
#pragma unroll
        for (int mf = 0; mf < 2; ++mf) {
            int r = r0 + mf * 16 + lrow;
            if (r > R - 1) r = R - 1;
            a[mf] = *(const bf16x8*)(X + (size_t)r * D + ks * 32 + lk8 * 8);
        }
#pragma unroll
        for (int nf = 0; nf < 8; ++nf) {
            int row = nf * 16 + lrow;
            int blk = ks * 4 + lk8;
            int idx = row * D + (blk ^ (row & 15)) * 8;
            bf16x8 b0 = *(const bf16x8*)(&Ws[0][idx]);
            bf16x8 b1 = *(const bf16x8*)(&Ws[1][idx]);
#pragma unroll
            for (int mf = 0; mf < 2; ++mf) {
                acc[0][mf][nf] = __builtin_amdgcn_mfma_f32_16x16x32_bf16(a[mf], b0, acc[0][mf][nf], 0, 0, 0);
                acc[1][mf][nf] = __builtin_amdgcn_mfma_f32_16x16x32_bf16(a[mf], b1, acc[1][mf][nf], 0, 0, 0);
            }
        }
    }

#pragma unroll
    for (int mf = 0; mf < 2; ++mf) {
        int rbase = r0 + mf * 16 + (lane >> 4) * 4;
#pragma unroll
        for (int e = 0; e < 4; ++e) {
            int r = rbase + e;
            if (r >= R) continue;
#pragma unroll
            for (int nf = 0; nf < 8; ++nf) {
                int col = nf * 16 + (lane & 15);
                o1[(size_t)r * D + col] = enc_fp8_1(acc[0][mf][nf][e] * s1);
                o2[(size_t)r * D + col] = (bf16)acc[1][mf][nf][e];
            }
        }
    }
}

// ---------------- PSI MFMA GEMM (K=256): v = act([X1 ; X2*fac]@Wf^T + fac*bf + addH) -----
__global__ __launch_bounds__(256) void gemm_psi(
    const bf16* __restrict__ X1, const bf16* __restrict__ X2,
    const float* __restrict__ rowfac, const float* __restrict__ Wf,
    const float* __restrict__ bf_, const bf16* __restrict__ addH,
    float* __restrict__ outF, unsigned char* __restrict__ out8, float s8,
    int R, int doRelu)
{
    __shared__ __align__(16) bf16 Ws[D * 256];   // 64 KB
    const int t = threadIdx.x;
    for (int g = t; g < D * 32; g += 256) {
        int row = g >> 5, blk = g & 31;
        const float* src = Wf + (size_t)row * 256 + blk * 8;
        float4 f0 = *(const float4*)(src);
        float4 f1 = *(const float4*)(src + 4);
        bf16x8 v = { (bf16)f0.x, (bf16)f0.y, (bf16)f0.z, (bf16)f0.w,
                     (bf16)f1.x, (bf16)f1.y, (bf16)f1.z, (bf16)f1.w };
        *(bf16x8*)(&Ws[row * 256 + (blk ^ (row & 15)) * 8]) = v;
    }
    __syncthreads();

    const int lane = t & 63, wave = t >> 6;
    const int lrow = lane & 15, lk8 = lane >> 4;
    const int r0 = blockIdx.x * 128 + wave * 32;

    int rr[2]; float fac[2];
#pragma unroll
    for (int mf = 0; mf < 2; ++mf) {
        rr[mf] = min(r0 + mf * 16 + lrow, R - 1);
        fac[mf] = rowfac[rr[mf]];
    }

    f32x4 acc[2][8] = {};
    for (int ks = 0; ks < 8; ++ks) {
        bf16x8 a[2];
#pragma unroll
        for (int mf = 0; mf < 2; ++mf) {
            if (ks < 4) {
                a[mf] = *(const bf16x8*)(X1 + (size_t)rr[mf] * D + ks * 32 + lk8 * 8);
            } else {
                bf16x8 m = *(const bf16x8*)(X2 + (size_t)rr[mf] * D + (ks - 4) * 32 + lk8 * 8);
#pragma unroll
                for (int c = 0; c < 8; ++c) a[mf][c] = (bf16)((float)m[c] * fac[mf]);
            }
        }
        bf16x8 b[8];
#pragma unroll
        for (int nf = 0; nf < 8; ++nf) {
            int row = nf * 16 + lrow;
            int blk = ks * 4 + lk8;
            b[nf] = *(const bf16x8*)(&Ws[row * 256 + (blk ^ (row & 15)) * 8]);
        }
#pragma unroll
        for (int mf = 0; mf < 2; ++mf)
#pragma unroll
            for (int nf = 0; nf < 8; ++nf)
                acc[mf][nf] = __builtin_amdgcn_mfma_f32_16x16x32_bf16(a[mf], b[nf], acc[mf][nf], 0, 0, 0);
    }

#pragma unroll
    for (int mf = 0; mf < 2; ++mf) {
        int rbase = r0 + mf * 16 + (lane >> 4) * 4;
#pragma unroll
        for (int e = 0; e < 4; ++e) {
            int r = rbase + e;
            if (r >= R) continue;
            float bs = rowfac[r];
#pragma unroll
            for (int nf = 0; nf < 8; ++nf) {
                int col = nf * 16 + (lane & 15);
                float v = acc[mf][nf][e] + bs * bf_[col];
                if (addH) v += (float)addH[(size_t)r * D + col];
                if (doRelu) v = fmaxf(v, 0.0f);
                if (outF) outF[(size_t)r * D + col] = v;
                if (out8) out8[(size_t)r * D + col] = enc_fp8_1(v * s8);
            }
        }
    }
}

// ---------------- bucket pass: append (pk, w) into fixed-capacity bucket staging ---------
__global__ __launch_bounds__(256) void bucket_pass(
    const int* __restrict__ ie, const int* __restrict__ iv,
    const int* __restrict__ er_r, const int* __restrict__ er_c, const float* __restrict__ er_v,
    const int* __restrict__ vr_r, const int* __restrict__ vr_c, const float* __restrict__ vr_v,
    const float* __restrict__ invDV, const float* __restrict__ invDE,
    int E, int nnzE, int nnzV,
    int4 rbb, int4 SHv, int NB,
    int* __restrict__ bcur, uint2* __restrict__ stg)
{
    __shared__ int h_cnt[1024];
    __shared__ int h_gb[1024];
    const int t = threadIdx.x;
    const int TH = 2 * E + nnzE + nnzV;
    const int base = blockIdx.x * BTILE;
    for (int i = t; i < NB; i += 256) h_cnt[i] = 0;
    __syncthreads();

    int pk[16], bl[16]; float wv[16];
#pragma unroll
    for (int j = 0; j < 16; ++j) {
        int gid = base + j * 256 + t;
        bl[j] = -1; wv[j] = 0.0f;
        if (gid >= TH) continue;
        int key, gs, r; float w;
        if (gid < E)               { key = ie[gid]; gs = iv[gid]; w = invDV[gs]; r = 0; }
        else if (gid < 2 * E)      { int i2 = gid - E; key = iv[i2]; gs = ie[i2]; w = invDE[gs]; r = 1; }
        else if (gid < 2 * E + nnzE) { int i2 = gid - 2 * E; key = er_r[i2]; gs = er_c[i2]; w = er_v[i2]; r = 2; }
        else                       { int i2 = gid - 2 * E - nnzE; key = vr_r[i2]; gs = vr_c[i2]; w = vr_v[i2]; r = 3; }
        int sh = pick4(SHv, r);
        int b = pick4(rbb, r) + (key >> sh);
        int lk = key & ((1 << sh) - 1);
        pk[j] = (lk << 17) | gs;
        int lr = atomicAdd(&h_cnt[b], 1);
        bl[j] = (b << 12) | lr;
        wv[j] = w;
    }
    __syncthreads();

    for (int b = t; b < NB; b += 256) {
        int c = h_cnt[b];
        if (c > 0) h_gb[b] = atomicAdd(&bcur[b], c);
    }
    __syncthreads();

#pragma unroll
    for (int j = 0; j < 16; ++j) {
        if (bl[j] < 0) continue;
        int b = bl[j] >> 12, lr = bl[j] & 4095;
        int pos = h_gb[b] + lr;
        if (pos < BCAP)
            stg[(size_t)b * BCAP + pos] = make_uint2((unsigned)pk[j], __float_as_uint(wv[j]));
    }
}

// ---------------- finalize: self-computed bucket base; local hist+scan -> off, sl_all ----
__global__ __launch_bounds__(256) void finalize_pass(
    int4 rbOff, int4 rbb, int4 SHv, int4 Kkeys, int NB,
    const int* __restrict__ bcur, const uint2* __restrict__ stg,
    int* __restrict__ off_all, uint2* __restrict__ sl_all)
{
    __shared__ int cnt_l[1024];
    __shared__ int off_l[1025];
    __shared__ int wsum[4], wpre[4];
    __shared__ int red[4];
    const int b = blockIdx.x, t = threadIdx.x;
    const int wid = t >> 6, lane = t & 63;
    // s0 = prefix sum of bcur[0..b)
    {
        int part = 0;
        for (int i = t; i < b; i += 256) part += bcur[i];
#pragma unroll
        for (int of = 1; of < 64; of <<= 1) part += __shfl_xor(part, of, 64);
        if (lane == 0) red[wid] = part;
        __syncthreads();
        if (t == 0) off_l[1024] = red[0] + red[1] + red[2] + red[3];  // stash s0
        __syncthreads();
    }
    const int s0 = off_l[1024];
    const int cntb = min(bcur[b], BCAP);
    const int s1 = s0 + cntb;
    const int r = (b >= rbb.w) ? 3 : (b >= rbb.z) ? 2 : (b >= rbb.y) ? 1 : 0;
    const int bloc = b - pick4(rbb, r);
    const int sh = pick4(SHv, r);
    const int rb = pick4(rbOff, r);
    const int K = pick4(Kkeys, r);
    const int k0 = bloc << sh;
    const int nk = min(1 << sh, K - k0);
    const uint2* my = stg + (size_t)b * BCAP;
    for (int i = t; i < nk; i += 256) cnt_l[i] = 0;
    __syncthreads();
    for (int i = t; i < cntb; i += 256)
        atomicAdd(&cnt_l[my[i].x >> 17], 1);
    __syncthreads();
    {
        int x[4], s = 0;
#pragma unroll
        for (int j = 0; j < 4; ++j) { int i = t * 4 + j; x[j] = (i < nk) ? cnt_l[i] : 0; s += x[j]; }
        int v = s;
#pragma unroll
        for (int of = 1; of < 64; of <<= 1) {
            int u = __shfl_up(v, of, 64);
            if (lane >= of) v += u;
        }
        if (lane == 63) wsum[wid] = v;
        __syncthreads();
        if (t == 0) { int a = 0; for (int i = 0; i < 4; ++i) { wpre[i] = a; a += wsum[i]; } }
        __syncthreads();
        int pre = wpre[wid] + (v - s);
#pragma unroll
        for (int j = 0; j < 4; ++j) { int i = t * 4 + j; if (i < nk) off_l[i] = pre; pre += x[j]; }
        if (t == 0) off_l[nk] = cntb;
    }
    __syncthreads();
    for (int i = t; i < nk; i += 256) off_all[rb + k0 + i] = s0 + off_l[i];
    if (t == 0 && k0 + nk == K) off_all[rb + K] = s1;
    for (int i = t; i < nk; i += 256) cnt_l[i] = 0;
    __syncthreads();
    for (int i = t; i < cntb; i += 256) {
        uint2 p = my[i];
        int lk = (int)(p.x >> 17), gs = (int)(p.x & 0x1FFFF);
        int lpos = off_l[lk] + atomicAdd(&cnt_l[lk], 1);
        sl_all[s0 + lpos] = make_uint2((unsigned)gs, p.y);
    }
}

// ---------------- CSR gather: 16-lane group per dest row, 8-slot unrolled ----------------
// packed slot stream sl[s] = (gs, w_bits); w used by KIND 0/1/7, ignored by KIND 2/6.
template<int KIND, int SRC8, int SRC28, int OUT8>
__global__ __launch_bounds__(256) void seg_gather(
    const unsigned char* __restrict__ src, int rsS, int ofS,
    const unsigned char* __restrict__ src2, int rsS2, int ofS2,
    const int* __restrict__ off, const uint2* __restrict__ sl,
    const bf16* __restrict__ auxH,
    unsigned char* __restrict__ outH, int rsO, int ofO,
    bf16* __restrict__ outH2,
    float* __restrict__ outF, float* __restrict__ rowfac,
    float postA, float post2, float postO, int R)
{
    const int r = blockIdx.x * 16 + (threadIdx.x >> 4);
    if (r >= R) return;
    const int lc = threadIdx.x & 15;
    const int s0 = off[r], s1 = off[r + 1];
    float acc[8] = {}, acc2[8] = {};
    float sd = 0.0f;
    const bool useW = (KIND == 0 || KIND == 1 || KIND == 7);

    int s = s0;
    for (; s + 8 <= s1; s += 8) {
        uint2 p[8]; float w[8];
#pragma unroll
        for (int j = 0; j < 8; ++j) p[j] = sl[s + j];
#pragma unroll
        for (int j = 0; j < 8; ++j) w[j] = useW ? __uint_as_float(p[j].y) : 1.0f;
        float v[8][8];
#pragma unroll
        for (int j = 0; j < 8; ++j) row_load<SRC8>(src, (int)p[j].x, rsS, ofS, lc, v[j]);
        if constexpr (KIND == 7) {
            float u[8][8];
#pragma unroll
            for (int j = 0; j < 8; ++j) row_load<SRC28>(src2, (int)p[j].x, rsS2, ofS2, lc, u[j]);
#pragma unroll
            for (int c = 0; c < 8; ++c) {
                float t0 = u[0][c] + u[1][c] + u[2][c] + u[3][c];
                float t1 = u[4][c] + u[5][c] + u[6][c] + u[7][c];
                acc2[c] += t0 + t1;
            }
            sd += w[0] + w[1] + w[2] + w[3] + w[4] + w[5] + w[6] + w[7];
        }
#pragma unroll
        for (int c = 0; c < 8; ++c) {
            float t0 = v[0][c] * w[0] + v[1][c] * w[1] + v[2][c] * w[2] + v[3][c] * w[3];
            float t1 = v[4][c] * w[4] + v[5][c] * w[5] + v[6][c] * w[6] + v[7][c] * w[7];
            acc[c] += t0 + t1;
        }
    }
    for (; s < s1; ++s) {
        uint2 p0 = sl[s];
        float w = useW ? __uint_as_float(p0.y) : 1.0f;
        float v0[8];
        row_load<SRC8>(src, (int)p0.x, rsS, ofS, lc, v0);
#pragma unroll
        for (int c = 0; c < 8; ++c) acc[c] += v0[c] * w;
        if constexpr (KIND == 7) {
            float u0[8];
            row_load<SRC28>(src2, (int)p0.x, rsS2, ofS2, lc, u0);
#pragma unroll
            for (int c = 0; c < 8; ++c) acc2[c] += u0[c];
            sd += w;
        }
    }

    const int cnt = s1 - s0;
    const float rs = 1.0f / (float)max(cnt, 1);

    if constexpr (KIND == 0) {
        float o[8];
#pragma unroll
        for (int c = 0; c < 8; ++c) o[c] = acc[c] * postA;
        if (auxH) {
            bf16x8 a = *(const bf16x8*)(auxH + (size_t)r * D + lc * 8);
#pragma unroll
            for (int c = 0; c < 8; ++c) o[c] += (float)a[c];
        }
        if constexpr (OUT8) {
#pragma unroll
            for (int c = 0; c < 8; ++c) o[c] *= postO;
            *(uint2*)(outH + (size_t)r * rsO + ofO + lc * 8) = enc_fp8x8(o);
        } else {
            bf16x8 w8;
#pragma unroll
            for (int c = 0; c < 8; ++c) w8[c] = (bf16)o[c];
            *(bf16x8*)(outH + (size_t)r * 256 + lc * 16) = w8;
        }
    } else if constexpr (KIND == 1 || KIND == 6) {
        float o[8];
#pragma unroll
        for (int c = 0; c < 8; ++c) o[c] = acc[c] * rs * postA;
        if constexpr (OUT8) {
#pragma unroll
            for (int c = 0; c < 8; ++c) o[c] *= postO;
            *(uint2*)(outH + (size_t)r * rsO + ofO + lc * 8) = enc_fp8x8(o);
        } else {
            bf16x8 w8;
#pragma unroll
            for (int c = 0; c < 8; ++c) w8[c] = (bf16)o[c];
            *(bf16x8*)(outH + (size_t)r * 256 + lc * 16) = w8;
        }
        if (KIND == 6 && lc == 0) rowfac[r] = (cnt > 0) ? 1.0f : 0.0f;
    } else if constexpr (KIND == 2) {
        float o[8];
#pragma unroll
        for (int c = 0; c < 8; ++c) o[c] = fmaxf(acc[c] * rs * postA, 0.0f);
        float4 o0 = { o[0], o[1], o[2], o[3] };
        float4 o1 = { o[4], o[5], o[6], o[7] };
        *(float4*)(outF + (size_t)r * D + lc * 8) = o0;
        *(float4*)(outF + (size_t)r * D + lc * 8 + 4) = o1;
        if constexpr (OUT8) {
#pragma unroll
            for (int c = 0; c < 8; ++c) o[c] *= postO;
            *(uint2*)(outH + (size_t)r * rsO + ofO + lc * 8) = enc_fp8x8(o);
        }
    } else {  // KIND 7
        bf16x8 w8, w2;
#pragma unroll
        for (int c = 0; c < 8; ++c) w8[c] = (bf16)(acc[c] * rs);
#pragma unroll
        for (int c = 0; c < 8; ++c) w2[c] = (bf16)(acc2[c] * rs * post2);
        *(bf16x8*)(outH + (size_t)r * 256 + lc * 16) = w8;
        *(bf16x8*)(outH2 + (size_t)r * D + lc * 8) = w2;
        if (lc == 0) rowfac[r] = sd * rs;
    }
}

extern "C" void kernel_launch(void* const* d_in, const int* in_sizes, int n_in,
                              void* d_out, int out_size, void* d_ws, size_t ws_size,
                              hipStream_t stream) {
    const float* vfeat  = (const float*)d_in[0];
    const float* efeat  = (const float*)d_in[1];
    const float* invDV  = (const float*)d_in[2];
    const float* invDE  = (const float*)d_in[3];
    const int*   inc_v  = (const int*)d_in[4];
    const int*   inc_e  = (const int*)d_in[5];
    const int*   eM_row = (const int*)d_in[6];
    const int*   eM_col = (const int*)d_in[7];
    const float* eM_val = (const float*)d_in[8];
    const int*   vM_row = (const int*)d_in[9];
    const int*   vM_col = (const int*)d_in[10];
    const float* vM_val = (const float*)d_in[11];
    const float* W_psi1 = (const float*)d_in[12];
    const float* b_psi1 = (const float*)d_in[13];
    const float* W_psi2 = (const float*)d_in[14];
    const float* b_psi2 = (const float*)d_in[15];
    const float* W_v    = (const float*)d_in[16];
    const float* W_e    = (const float*)d_in[17];

    const int N = in_sizes[0] / D;
    const int M = in_sizes[1] / D;
    const int E = in_sizes[4];
    const int nnzE = in_sizes[6];
    const int nnzV = in_sizes[9];
    const int TH = 2 * E + nnzE + nnzV;

    float* out = (float*)d_out;
    float* vfeat_new = out;                     // N*D
    float* efeat_new = out + (size_t)N * D;     // M*D

    const int T = 2 * M + 2 * N + 4;

    // fp8 storage scales (keep values in e4m3 sweet range)
    const float S_B = 16.0f;   // vf2preW
    const float S_C = 64.0f;   // vf2W
    const float S_N = 8.0f;    // vnew
    const float S_W = 8.0f;    // efW_e
    const float S_A = 16.0f;   // A'

    // bucket geometry
    const int shE = 8, shV = 10, shEr = 9, shVr = 10;
    auto cdiv = [](int a, int b) { return (a + b - 1) / b; };
    const int nbE  = cdiv(M, 1 << shE);
    const int nbV  = cdiv(N, 1 << shV);
    const int nbEr = cdiv(M, 1 << shEr);
    const int nbVr = cdiv(N, 1 << shVr);
    const int NB = nbE + nbV + nbEr + nbVr;   // 315 (<=1024 required)
    const int4 rbb   = { 0, nbE, nbE + nbV, nbE + nbV + nbEr };
    const int4 SHv   = { shE, shV, shEr, shVr };
    const int4 Kkeys = { M, N, M, N };
    const int bV  = M + 1;
    const int bEr = bV + (N + 1);
    const int bVr = bEr + (M + 1);
    const int4 rbOff = { 0, bV, bEr, bVr };

    // workspace layout (8B-aligned large arrays first)
    unsigned char* nP8 = (unsigned char*)d_ws;          // N*256B  [vfeat8 | vf2W8->vnew8]
    unsigned char* nB8 = nP8 + (size_t)N * 256;         // N*128B  vf2preW8 (x16)
    bf16* mE  = (bf16*)(nB8 + (size_t)N * 128);         // M*D  efeatH
    unsigned char* mWe8 = (unsigned char*)(mE + (size_t)M * D);  // M*128B efW_e8 -> A'8
    bf16* mV  = (bf16*)(mWe8 + (size_t)M * 128);        // M*D  efW_v
    bf16* mB  = mV + (size_t)M * D;                     // M*D  _efeatV
    bf16* mC  = mB + (size_t)M * D;                     // M*D  ef3preW
    bf16* mP  = mC + (size_t)M * D;                     // M*D  psi gather out (1 then 2)
    unsigned char* mA8 = mWe8;                          // alias: A'8 after efW_e8 dead
    float* W1f = (float*)(mP + (size_t)M * D);          // 128*256
    float* W2f = W1f + 128 * 256;                       // 128*256
    float* b1f = W2f + 128 * 256;                       // 128
    float* b2f = b1f + 128;                             // 128
    float* rowfac = b2f + 128;                          // M  (M*4 divisible by 8)
    uint2* sl_all = (uint2*)(rowfac + M);               // TH packed (gs,w)
    uint2* stg    = sl_all + TH;                        // NB*BCAP packed staging
    int* off_all  = (int*)(stg + (size_t)NB * BCAP);    // T
    int* bcur     = off_all + T;                        // NB (memset)

    int* offE  = off_all;
    int* offV  = off_all + bV;
    int* offEr = off_all + bEr;
    int* offVr = off_all + bVr;

    const dim3 TB(256);

    // ---- CSR build: bucketed append (fixed cap) -> per-bucket finalize (self-scan) ----
    hipMemsetAsync(bcur, 0, (size_t)NB * 4, stream);
    bucket_pass<<<cdiv(TH, BTILE), TB, 0, stream>>>(
        inc_e, inc_v, eM_row, eM_col, eM_val, vM_row, vM_col, vM_val,
        invDV, invDE, E, nnzE, nnzV, rbb, SHv, NB, bcur, stg);
    finalize_pass<<<NB, TB, 0, stream>>>(
        rbOff, rbb, SHv, Kkeys, NB, bcur, stg, off_all, sl_all);

    // ---- fused prep: fp8(vfeat), bf16(efeat), weight folds ----
    const int nb8 = cdiv(N * D / 8, 256), nb16 = cdiv(M * D / 4, 256);
    prep_all<<<nb8 + nb16 + 257, TB, 0, stream>>>(
        vfeat, N * D / 8, nP8, 256, efeat, M * D / 4, mE,
        W_v, W_psi1, b_psi1, W_e, W_psi2, b_psi2,
        W1f, b1f, W2f, b2f, nb8, nb16);

    // ---- pipeline (Wv/We-transformed space; fp8 on attenuated paths) ----
    // efW_e8 = fp8(efeat @ W_e^T * 8) ; efW_v = bf16(efeat @ W_v^T)
    gemm_dual<<<cdiv(M, 128), TB, 0, stream>>>(mE, W_e, W_v, mWe8, S_W, mV, M);
    // vf2preW8 = fp8(mean_v(efW_e[inc_e]*invDE) * 16)   [w packed in sl]
    seg_gather<1, 1, 0, 1><<<cdiv(N, 16), TB, 0, stream>>>(
        mWe8, 128, 0, nullptr, 0, 0, offV, sl_all, nullptr,
        nB8, 128, 0, nullptr, nullptr, nullptr, 1.0f / S_W, 1.0f, S_B, N);
    // vf2W8 = fp8(spmm_V(vf2preW) * 64) -> nP8[+128]
    seg_gather<0, 1, 0, 1><<<cdiv(N, 16), TB, 0, stream>>>(
        nB8, 128, 0, nullptr, 0, 0, offVr, sl_all, nullptr,
        nP8, 256, 128, nullptr, nullptr, nullptr, 1.0f / S_B, 1.0f, S_C, N);
    // FUSED psi1: mP = mean_w(vfeat8*dv); mC = ef3preW = mean(vf2W)/64; rowfac = sd/cnt
    seg_gather<7, 1, 1, 0><<<cdiv(M, 16), TB, 0, stream>>>(
        nP8, 256, 0, nP8, 256, 128, offE, sl_all, nullptr,
        (unsigned char*)mP, 256, 0, mC, nullptr, rowfac, 1.0f, 1.0f / S_C, 1.0f, M);
    // A'8 = fp8(([mP ; mE*fac] @ W1f^T + fac*b1f) * 16) -> mA8 (aliases mWe8)
    gemm_psi<<<cdiv(M, 128), TB, 0, stream>>>(
        mP, mE, rowfac, W1f, b1f, nullptr, nullptr, mA8, S_A, M, 0);
    // _efeatV = spmm_E(A')/16 + efW_v -> mB (bf16; feeds outputs, stays bf16)
    seg_gather<0, 1, 0, 0><<<cdiv(M, 16), TB, 0, stream>>>(
        mA8, 128, 0, nullptr, 0, 0, offEr, sl_all, mV,
        (unsigned char*)mB, 256, 0, nullptr, nullptr, nullptr, 1.0f / S_A, 1.0f, 1.0f, M);
    // vfeat_new = relu(mean_v(_efeatV)) -> d_out f32 + vnew8 (nP8[+128], x8; vf2W dead)
    seg_gather<2, 0, 0, 1><<<cdiv(N, 16), TB, 0, stream>>>(
        (unsigned char*)mB, 256, 0, nullptr, 0, 0, offV, sl_all, nullptr,
        nP8, 256, 128, nullptr, vfeat_new, nullptr, 1.0f, 1.0f, S_N, N);
    // psi2: mP = mean(vnew8)/8; rowfac = [cnt>0]
    seg_gather<6, 1, 0, 0><<<cdiv(M, 16), TB, 0, stream>>>(
        nP8, 256, 128, nullptr, 0, 0, offE, sl_all, nullptr,
        (unsigned char*)mP, 256, 0, nullptr, nullptr, rowfac, 1.0f / S_N, 1.0f, 1.0f, M);
    // efeat_new = relu([mP ; mE*fac] @ W2f^T + fac*b2f + ef3preW) -> d_out
    gemm_psi<<<cdiv(M, 128), TB, 0, stream>>>(
        mP, mE, rowfac, W2f, b2f, mC, efeat_new, nullptr, 1.0f, M, 1);
}

// Round 16
// 252.936 us; speedup vs baseline: 1.0863x; 1.0863x over previous
//
#include <hip/hip_runtime.h>

#define D 128
#define BTILE 4096      // items per bucket block (16/thread)
#define BCAP 12288      // fixed per-bucket staging capacity (mean ~5-6.4k, sigma ~80)

typedef __bf16 bf16;
typedef __attribute__((ext_vector_type(4))) __bf16 bf16x4;
typedef __attribute__((ext_vector_type(8))) __bf16 bf16x8;
typedef __attribute__((ext_vector_type(4))) float f32x4;
typedef __attribute__((ext_vector_type(2))) float f32x2;

__device__ __forceinline__ int pick4(int4 v, int r) {
    return r == 0 ? v.x : r == 1 ? v.y : r == 2 ? v.z : v.w;
}

// ---------------- fp8 e4m3 helpers (HW cvt if available, bit-op fallback) ----------------
#if defined(__has_builtin)
#  if __has_builtin(__builtin_amdgcn_cvt_pk_f32_fp8) && __has_builtin(__builtin_amdgcn_cvt_pk_fp8_f32)
#    define HWFP8 1
#  endif
#endif
#ifndef HWFP8
#  define HWFP8 0
#endif

__device__ __forceinline__ void dec_fp8x8(uint2 p, float* o) {
#if HWFP8
    f32x2 a = __builtin_amdgcn_cvt_pk_f32_fp8((int)p.x, false);
    f32x2 b = __builtin_amdgcn_cvt_pk_f32_fp8((int)p.x, true);
    f32x2 c = __builtin_amdgcn_cvt_pk_f32_fp8((int)p.y, false);
    f32x2 d = __builtin_amdgcn_cvt_pk_f32_fp8((int)p.y, true);
    o[0]=a.x; o[1]=a.y; o[2]=b.x; o[3]=b.y; o[4]=c.x; o[5]=c.y; o[6]=d.x; o[7]=d.y;
#else
    unsigned w0 = p.x, w1 = p.y;
#pragma unroll
    for (int k = 0; k < 8; ++k) {
        unsigned b8 = ((k < 4 ? w0 : w1) >> ((k & 3) * 8)) & 0xffu;
        unsigned bits = ((b8 & 0x80u) << 24) | ((b8 & 0x7fu) << 20);
        o[k] = __uint_as_float(bits) * 0x1p+120f;
    }
#endif
}

#if !HWFP8
__device__ __forceinline__ unsigned enc_fp8_sw(float x) {
    unsigned u = __float_as_uint(x);
    unsigned s = (u >> 24) & 0x80u;
    int e = (int)((u >> 23) & 0xffu) - 127;
    unsigned m = u & 0x7fffffu;
    if (e < -6) return s;
    unsigned mant = m >> 20;
    unsigned rest = m & 0xfffffu;
    mant += (rest > 0x80000u) || (rest == 0x80000u && (mant & 1u));
    unsigned E = (unsigned)(e + 7);
    if (mant == 8u) { mant = 0u; E += 1u; }
    if (E > 15u || (E == 15u && mant > 6u)) return s | 0x7eu;
    return s | (E << 3) | mant;
}
#endif

__device__ __forceinline__ uint2 enc_fp8x8(const float* v) {
#if HWFP8
    int lo = 0, hi = 0;
    lo = __builtin_amdgcn_cvt_pk_fp8_f32(v[0], v[1], lo, false);
    lo = __builtin_amdgcn_cvt_pk_fp8_f32(v[2], v[3], lo, true);
    hi = __builtin_amdgcn_cvt_pk_fp8_f32(v[4], v[5], hi, false);
    hi = __builtin_amdgcn_cvt_pk_fp8_f32(v[6], v[7], hi, true);
    return make_uint2((unsigned)lo, (unsigned)hi);
#else
    unsigned w0 = 0, w1 = 0;
#pragma unroll
    for (int k = 0; k < 4; ++k) w0 |= enc_fp8_sw(v[k]) << (k * 8);
#pragma unroll
    for (int k = 0; k < 4; ++k) w1 |= enc_fp8_sw(v[4 + k]) << (k * 8);
    return make_uint2(w0, w1);
#endif
}

__device__ __forceinline__ unsigned char enc_fp8_1(float x) {
#if HWFP8
    int v = __builtin_amdgcn_cvt_pk_fp8_f32(x, 0.0f, 0, false);
    return (unsigned char)(v & 0xff);
#else
    return (unsigned char)enc_fp8_sw(x);
#endif
}

// byte-addressed row load; F8: 8B/lane fp8 -> 8 floats, else 16B/lane bf16 -> 8 floats
template<int F8>
__device__ __forceinline__ void row_load(const unsigned char* src, int g, int rs, int of,
                                         int lc, float* o) {
    if constexpr (F8) {
        uint2 p = *(const uint2*)(src + (size_t)g * rs + of + lc * 8);
        dec_fp8x8(p, o);
    } else {
        bf16x8 p = *(const bf16x8*)(src + (size_t)g * rs + of + lc * 16);
#pragma unroll
        for (int k = 0; k < 8; ++k) o[k] = (float)p[k];
    }
}

// ---------------- fused prep: fp8(vfeat), bf16(efeat), weight folds ----------------------
__global__ __launch_bounds__(256) void prep_all(
    const float* __restrict__ vfeat, int n8v, unsigned char* __restrict__ nP8, int rs8,
    const float* __restrict__ efeat, int n4e, bf16* __restrict__ mE,
    const float* __restrict__ Wv, const float* __restrict__ W1, const float* __restrict__ b1,
    const float* __restrict__ We, const float* __restrict__ W2, const float* __restrict__ b2,
    float* __restrict__ W1f, float* __restrict__ b1f,
    float* __restrict__ W2f, float* __restrict__ b2f,
    int nb8, int nb16)
{
    const int b = blockIdx.x, t = threadIdx.x;
    if (b < nb8) {
        int i = b * 256 + t;
        if (i >= n8v) return;
        float4 f0 = *(const float4*)(vfeat + (size_t)i * 8);
        float4 f1 = *(const float4*)(vfeat + (size_t)i * 8 + 4);
        float v[8] = { f0.x, f0.y, f0.z, f0.w, f1.x, f1.y, f1.z, f1.w };
        int row = i >> 4, lane = i & 15;
        *(uint2*)(nP8 + (size_t)row * rs8 + lane * 8) = enc_fp8x8(v);
    } else if (b < nb8 + nb16) {
        int i = (b - nb8) * 256 + t;
        if (i >= n4e) return;
        float4 f = ((const float4*)efeat)[i];
        bf16x4 v = { (bf16)f.x, (bf16)f.y, (bf16)f.z, (bf16)f.w };
        ((bf16x4*)mE)[i] = v;
    } else {
        int gid = (b - nb8 - nb16) * 256 + t;
        if (gid < 65536) {
            int which = gid >> 15;
            int i = (gid >> 8) & 127;
            int j = gid & 255;
            const float* A = which ? We : Wv;
            const float* B = which ? W2 : W1;
            float s = 0.0f;
            for (int k = 0; k < 128; ++k) s += A[i * 128 + k] * B[k * 256 + j];
            (which ? W2f : W1f)[i * 256 + j] = s;
        } else if (gid < 65536 + 256) {
            int tt = gid - 65536, which = tt >> 7, i = tt & 127;
            const float* A = which ? We : Wv;
            const float* B = which ? b2 : b1;
            float s = 0.0f;
            for (int k = 0; k < 128; ++k) s += A[i * 128 + k] * B[k];
            (which ? b2f : b1f)[i] = s;
        }
    }
}

// ---------------- DUAL MFMA GEMM (K=128): o1 = fp8(X@W1^T * s1), o2 = bf16(X@W2^T) -------
__global__ __launch_bounds__(256) void gemm_dual(
    const bf16* __restrict__ X, const float* __restrict__ W1, const float* __restrict__ W2,
    unsigned char* __restrict__ o1, float s1, bf16* __restrict__ o2, int R)
{
    __shared__ __align__(16) bf16 Ws[2][D * D];   // 64 KB
    const int t = threadIdx.x;
    for (int g = t; g < D * 16; g += 256) {
        int row = g >> 4, blk = g & 15;
        int sb = (blk ^ (row & 15)) * 8;
#pragma unroll
        for (int wsel = 0; wsel < 2; ++wsel) {
            const float* src = (wsel ? W2 : W1) + (size_t)row * D + blk * 8;
            float4 f0 = *(const float4*)(src);
            float4 f1 = *(const float4*)(src + 4);
            bf16x8 v = { (bf16)f0.x, (bf16)f0.y, (bf16)f0.z, (bf16)f0.w,
                         (bf16)f1.x, (bf16)f1.y, (bf16)f1.z, (bf16)f1.w };
            *(bf16x8*)(&Ws[wsel][row * D + sb]) = v;
        }
    }
    __syncthreads();

    const int lane = t & 63, wave = t >> 6;
    const int lrow = lane & 15, lk8 = lane >> 4;
    const int r0 = blockIdx.x * 128 + wave * 32;

    f32x4 acc[2][2][8] = {};   // [wsel][mf][nf]
    for (int ks = 0; ks < 4; ++ks) {
        bf16x8 a[2];
#pragma unroll
        for (int mf = 0; mf < 2; ++mf) {
            int r = r0 + mf * 16 + lrow;
            if (r > R - 1) r = R - 1;
            a[mf] = *(const bf16x8*)(X + (size_t)r * D + ks * 32 + lk8 * 8);
        }
#pragma unroll
        for (int nf = 0; nf < 8; ++nf) {
            int row = nf * 16 + lrow;
            int blk = ks * 4 + lk8;
            int idx = row * D + (blk ^ (row & 15)) * 8;
            bf16x8 b0 = *(const bf16x8*)(&Ws[0][idx]);
            bf16x8 b1 = *(const bf16x8*)(&Ws[1][idx]);
#pragma unroll
            for (int mf = 0; mf < 2; ++mf) {
                acc[0][mf][nf] = __builtin_amdgcn_mfma_f32_16x16x32_bf16(a[mf], b0, acc[0][mf][nf], 0, 0, 0);
                acc[1][mf][nf] = __builtin_amdgcn_mfma_f32_16x16x32_bf16(a[mf], b1, acc[1][mf][nf], 0, 0, 0);
            }
        }
    }

#pragma unroll
    for (int mf = 0; mf < 2; ++mf) {
        int rbase = r0 + mf * 16 + (lane >> 4) * 4;
#pragma unroll
        for (int e = 0; e < 4; ++e) {
            int r = rbase + e;
            if (r >= R) continue;
#pragma unroll
            for (int nf = 0; nf < 8; ++nf) {
                int col = nf * 16 + (lane & 15);
                o1[(size_t)r * D + col] = enc_fp8_1(acc[0][mf][nf][e] * s1);
                o2[(size_t)r * D + col] = (bf16)acc[1][mf][nf][e];
            }
        }
    }
}

// ---------------- PSI MFMA GEMM (K=256): v = act([X1 ; X2*fac]@Wf^T + fac*bf + addH) -----
__global__ __launch_bounds__(256) void gemm_psi(
    const bf16* __restrict__ X1, const bf16* __restrict__ X2,
    const float* __restrict__ rowfac, const float* __restrict__ Wf,
    const float* __restrict__ bf_, const bf16* __restrict__ addH,
    float* __restrict__ outF, unsigned char* __restrict__ out8, float s8,
    int R, int doRelu)
{
    __shared__ __align__(16) bf16 Ws[D * 256];   // 64 KB
    const int t = threadIdx.x;
    for (int g = t; g < D * 32; g += 256) {
        int row = g >> 5, blk = g & 31;
        const float* src = Wf + (size_t)row * 256 + blk * 8;
        float4 f0 = *(const float4*)(src);
        float4 f1 = *(const float4*)(src + 4);
        bf16x8 v = { (bf16)f0.x, (bf16)f0.y, (bf16)f0.z, (bf16)f0.w,
                     (bf16)f1.x, (bf16)f1.y, (bf16)f1.z, (bf16)f1.w };
        *(bf16x8*)(&Ws[row * 256 + (blk ^ (row & 15)) * 8]) = v;
    }
    __syncthreads();

    const int lane = t & 63, wave = t >> 6;
    const int lrow = lane & 15, lk8 = lane >> 4;
    const int r0 = blockIdx.x * 128 + wave * 32;

    int rr[2]; float fac[2];
#pragma unroll
    for (int mf = 0; mf < 2; ++mf) {
        rr[mf] = min(r0 + mf * 16 + lrow, R - 1);
        fac[mf] = rowfac[rr[mf]];
    }

    f32x4 acc[2][8] = {};
    for (int ks = 0; ks < 8; ++ks) {
        bf16x8 a[2];
#pragma unroll
        for (int mf = 0; mf < 2; ++mf) {
            if (ks < 4) {
                a[mf] = *(const bf16x8*)(X1 + (size_t)rr[mf] * D + ks * 32 + lk8 * 8);
            } else {
                bf16x8 m = *(const bf16x8*)(X2 + (size_t)rr[mf] * D + (ks - 4) * 32 + lk8 * 8);
#pragma unroll
                for (int c = 0; c < 8; ++c) a[mf][c] = (bf16)((float)m[c] * fac[mf]);
            }
        }
        bf16x8 b[8];
#pragma unroll
        for (int nf = 0; nf < 8; ++nf) {
            int row = nf * 16 + lrow;
            int blk = ks * 4 + lk8;
            b[nf] = *(const bf16x8*)(&Ws[row * 256 + (blk ^ (row & 15)) * 8]);
        }
#pragma unroll
        for (int mf = 0; mf < 2; ++mf)
#pragma unroll
            for (int nf = 0; nf < 8; ++nf)
                acc[mf][nf] = __builtin_amdgcn_mfma_f32_16x16x32_bf16(a[mf], b[nf], acc[mf][nf], 0, 0, 0);
    }

#pragma unroll
    for (int mf = 0; mf < 2; ++mf) {
        int rbase = r0 + mf * 16 + (lane >> 4) * 4;
#pragma unroll
        for (int e = 0; e < 4; ++e) {
            int r = rbase + e;
            if (r >= R) continue;
            float bs = rowfac[r];
#pragma unroll
            for (int nf = 0; nf < 8; ++nf) {
                int col = nf * 16 + (lane & 15);
                float v = acc[mf][nf][e] + bs * bf_[col];
                if (addH) v += (float)addH[(size_t)r * D + col];
                if (doRelu) v = fmaxf(v, 0.0f);
                if (outF) outF[(size_t)r * D + col] = v;
                if (out8) out8[(size_t)r * D + col] = enc_fp8_1(v * s8);
            }
        }
    }
}

// ---------------- bucket pass: append (pk, w) into fixed-capacity bucket staging ---------
__global__ __launch_bounds__(256) void bucket_pass(
    const int* __restrict__ ie, const int* __restrict__ iv,
    const int* __restrict__ er_r, const int* __restrict__ er_c, const float* __restrict__ er_v,
    const int* __restrict__ vr_r, const int* __restrict__ vr_c, const float* __restrict__ vr_v,
    const float* __restrict__ invDV, const float* __restrict__ invDE,
    int E, int nnzE, int nnzV,
    int4 rbb, int4 SHv, int NB,
    int* __restrict__ bcur, uint2* __restrict__ stg)
{
    __shared__ int h_cnt[1024];
    __shared__ int h_gb[1024];
    const int t = threadIdx.x;
    const int TH = 2 * E + nnzE + nnzV;
    const int base = blockIdx.x * BTILE;
    for (int i = t; i < NB; i += 256) h_cnt[i] = 0;
    __syncthreads();

    int pk[16], bl[16]; float wv[16];
#pragma unroll
    for (int j = 0; j < 16; ++j) {
        int gid = base + j * 256 + t;
        bl[j] = -1; wv[j] = 0.0f;
        if (gid >= TH) continue;
        int key, gs, r; float w;
        if (gid < E)               { key = ie[gid]; gs = iv[gid]; w = invDV[gs]; r = 0; }
        else if (gid < 2 * E)      { int i2 = gid - E; key = iv[i2]; gs = ie[i2]; w = invDE[gs]; r = 1; }
        else if (gid < 2 * E + nnzE) { int i2 = gid - 2 * E; key = er_r[i2]; gs = er_c[i2]; w = er_v[i2]; r = 2; }
        else                       { int i2 = gid - 2 * E - nnzE; key = vr_r[i2]; gs = vr_c[i2]; w = vr_v[i2]; r = 3; }
        int sh = pick4(SHv, r);
        int b = pick4(rbb, r) + (key >> sh);
        int lk = key & ((1 << sh) - 1);
        pk[j] = (lk << 17) | gs;
        int lr = atomicAdd(&h_cnt[b], 1);
        bl[j] = (b << 12) | lr;
        wv[j] = w;
    }
    __syncthreads();

    for (int b = t; b < NB; b += 256) {
        int c = h_cnt[b];
        if (c > 0) h_gb[b] = atomicAdd(&bcur[b], c);
    }
    __syncthreads();

#pragma unroll
    for (int j = 0; j < 16; ++j) {
        if (bl[j] < 0) continue;
        int b = bl[j] >> 12, lr = bl[j] & 4095;
        int pos = h_gb[b] + lr;
        if (pos < BCAP)
            stg[(size_t)b * BCAP + pos] = make_uint2((unsigned)pk[j], __float_as_uint(wv[j]));
    }
}

// ---------------- finalize: self-computed bucket base; local hist+scan -> off, sl_all ----
__global__ __launch_bounds__(256) void finalize_pass(
    int4 rbOff, int4 rbb, int4 SHv, int4 Kkeys, int NB,
    const int* __restrict__ bcur, const uint2* __restrict__ stg,
    int* __restrict__ off_all, uint2* __restrict__ sl_all)
{
    __shared__ int cnt_l[1024];
    __shared__ int off_l[1025];
    __shared__ int wsum[4], wpre[4];
    __shared__ int red[4];
    const int b = blockIdx.x, t = threadIdx.x;
    const int wid = t >> 6, lane = t & 63;
    // s0 = prefix sum of bcur[0..b)
    {
        int part = 0;
        for (int i = t; i < b; i += 256) part += bcur[i];
#pragma unroll
        for (int of = 1; of < 64; of <<= 1) part += __shfl_xor(part, of, 64);
        if (lane == 0) red[wid] = part;
        __syncthreads();
        if (t == 0) off_l[1024] = red[0] + red[1] + red[2] + red[3];  // stash s0
        __syncthreads();
    }
    const int s0 = off_l[1024];
    const int cntb = min(bcur[b], BCAP);
    const int s1 = s0 + cntb;
    const int r = (b >= rbb.w) ? 3 : (b >= rbb.z) ? 2 : (b >= rbb.y) ? 1 : 0;
    const int bloc = b - pick4(rbb, r);
    const int sh = pick4(SHv, r);
    const int rb = pick4(rbOff, r);
    const int K = pick4(Kkeys, r);
    const int k0 = bloc << sh;
    const int nk = min(1 << sh, K - k0);
    const uint2* my = stg + (size_t)b * BCAP;
    for (int i = t; i < nk; i += 256) cnt_l[i] = 0;
    __syncthreads();
    for (int i = t; i < cntb; i += 256)
        atomicAdd(&cnt_l[my[i].x >> 17], 1);
    __syncthreads();
    {
        int x[4], s = 0;
#pragma unroll
        for (int j = 0; j < 4; ++j) { int i = t * 4 + j; x[j] = (i < nk) ? cnt_l[i] : 0; s += x[j]; }
        int v = s;
#pragma unroll
        for (int of = 1; of < 64; of <<= 1) {
            int u = __shfl_up(v, of, 64);
            if (lane >= of) v += u;
        }
        if (lane == 63) wsum[wid] = v;
        __syncthreads();
        if (t == 0) { int a = 0; for (int i = 0; i < 4; ++i) { wpre[i] = a; a += wsum[i]; } }
        __syncthreads();
        int pre = wpre[wid] + (v - s);
#pragma unroll
        for (int j = 0; j < 4; ++j) { int i = t * 4 + j; if (i < nk) off_l[i] = pre; pre += x[j]; }
        if (t == 0) off_l[nk] = cntb;
    }
    __syncthreads();
    for (int i = t; i < nk; i += 256) off_all[rb + k0 + i] = s0 + off_l[i];
    if (t == 0 && k0 + nk == K) off_all[rb + K] = s1;
    for (int i = t; i < nk; i += 256) cnt_l[i] = 0;
    __syncthreads();
    for (int i = t; i < cntb; i += 256) {
        uint2 p = my[i];
        int lk = (int)(p.x >> 17), gs = (int)(p.x & 0x1FFFF);
        int lpos = off_l[lk] + atomicAdd(&cnt_l[lk], 1);
        sl_all[s0 + lpos] = make_uint2((unsigned)gs, p.y);
    }
}

// ---------------- CSR gather: 16-lane group per dest row, 4-slot unrolled ----------------
// packed slot stream sl[s] = (gs, w_bits); w used by KIND 0/1/7, ignored by KIND 2/6.
template<int KIND, int SRC8, int SRC28, int OUT8>
__global__ __launch_bounds__(256) void seg_gather(
    const unsigned char* __restrict__ src, int rsS, int ofS,
    const unsigned char* __restrict__ src2, int rsS2, int ofS2,
    const int* __restrict__ off, const uint2* __restrict__ sl,
    const bf16* __restrict__ auxH,
    unsigned char* __restrict__ outH, int rsO, int ofO,
    bf16* __restrict__ outH2,
    float* __restrict__ outF, float* __restrict__ rowfac,
    float postA, float post2, float postO, int R)
{
    const int r = blockIdx.x * 16 + (threadIdx.x >> 4);
    if (r >= R) return;
    const int lc = threadIdx.x & 15;
    const int s0 = off[r], s1 = off[r + 1];
    float acc[8] = {}, acc2[8] = {};
    float sd = 0.0f;
    const bool useW = (KIND == 0 || KIND == 1 || KIND == 7);

    int s = s0;
    for (; s + 4 <= s1; s += 4) {
        uint2 p0 = sl[s + 0], p1 = sl[s + 1], p2 = sl[s + 2], p3 = sl[s + 3];
        float w0 = useW ? __uint_as_float(p0.y) : 1.0f;
        float w1 = useW ? __uint_as_float(p1.y) : 1.0f;
        float w2 = useW ? __uint_as_float(p2.y) : 1.0f;
        float w3 = useW ? __uint_as_float(p3.y) : 1.0f;
        float v0[8], v1[8], v2[8], v3[8];
        row_load<SRC8>(src, (int)p0.x, rsS, ofS, lc, v0);
        row_load<SRC8>(src, (int)p1.x, rsS, ofS, lc, v1);
        row_load<SRC8>(src, (int)p2.x, rsS, ofS, lc, v2);
        row_load<SRC8>(src, (int)p3.x, rsS, ofS, lc, v3);
        if constexpr (KIND == 7) {
            float u0[8], u1[8], u2[8], u3[8];
            row_load<SRC28>(src2, (int)p0.x, rsS2, ofS2, lc, u0);
            row_load<SRC28>(src2, (int)p1.x, rsS2, ofS2, lc, u1);
            row_load<SRC28>(src2, (int)p2.x, rsS2, ofS2, lc, u2);
            row_load<SRC28>(src2, (int)p3.x, rsS2, ofS2, lc, u3);
#pragma unroll
            for (int c = 0; c < 8; ++c) acc2[c] += u0[c] + u1[c] + u2[c] + u3[c];
            sd += w0 + w1 + w2 + w3;
        }
#pragma unroll
        for (int c = 0; c < 8; ++c)
            acc[c] += v0[c] * w0 + v1[c] * w1 + v2[c] * w2 + v3[c] * w3;
    }
    for (; s < s1; ++s) {
        uint2 p0 = sl[s];
        float w = useW ? __uint_as_float(p0.y) : 1.0f;
        float v0[8];
        row_load<SRC8>(src, (int)p0.x, rsS, ofS, lc, v0);
#pragma unroll
        for (int c = 0; c < 8; ++c) acc[c] += v0[c] * w;
        if constexpr (KIND == 7) {
            float u0[8];
            row_load<SRC28>(src2, (int)p0.x, rsS2, ofS2, lc, u0);
#pragma unroll
            for (int c = 0; c < 8; ++c) acc2[c] += u0[c];
            sd += w;
        }
    }

    const int cnt = s1 - s0;
    const float rs = 1.0f / (float)max(cnt, 1);

    if constexpr (KIND == 0) {
        float o[8];
#pragma unroll
        for (int c = 0; c < 8; ++c) o[c] = acc[c] * postA;
        if (auxH) {
            bf16x8 a = *(const bf16x8*)(auxH + (size_t)r * D + lc * 8);
#pragma unroll
            for (int c = 0; c < 8; ++c) o[c] += (float)a[c];
        }
        if constexpr (OUT8) {
#pragma unroll
            for (int c = 0; c < 8; ++c) o[c] *= postO;
            *(uint2*)(outH + (size_t)r * rsO + ofO + lc * 8) = enc_fp8x8(o);
        } else {
            bf16x8 w8;
#pragma unroll
            for (int c = 0; c < 8; ++c) w8[c] = (bf16)o[c];
            *(bf16x8*)(outH + (size_t)r * 256 + lc * 16) = w8;
        }
    } else if constexpr (KIND == 1 || KIND == 6) {
        float o[8];
#pragma unroll
        for (int c = 0; c < 8; ++c) o[c] = acc[c] * rs * postA;
        if constexpr (OUT8) {
#pragma unroll
            for (int c = 0; c < 8; ++c) o[c] *= postO;
            *(uint2*)(outH + (size_t)r * rsO + ofO + lc * 8) = enc_fp8x8(o);
        } else {
            bf16x8 w8;
#pragma unroll
            for (int c = 0; c < 8; ++c) w8[c] = (bf16)o[c];
            *(bf16x8*)(outH + (size_t)r * 256 + lc * 16) = w8;
        }
        if (KIND == 6 && lc == 0) rowfac[r] = (cnt > 0) ? 1.0f : 0.0f;
    } else if constexpr (KIND == 2) {
        float o[8];
#pragma unroll
        for (int c = 0; c < 8; ++c) o[c] = fmaxf(acc[c] * rs * postA, 0.0f);
        float4 o0 = { o[0], o[1], o[2], o[3] };
        float4 o1 = { o[4], o[5], o[6], o[7] };
        *(float4*)(outF + (size_t)r * D + lc * 8) = o0;
        *(float4*)(outF + (size_t)r * D + lc * 8 + 4) = o1;
        if constexpr (OUT8) {
#pragma unroll
            for (int c = 0; c < 8; ++c) o[c] *= postO;
            *(uint2*)(outH + (size_t)r * rsO + ofO + lc * 8) = enc_fp8x8(o);
        }
    } else {  // KIND 7
        bf16x8 w8, w2;
#pragma unroll
        for (int c = 0; c < 8; ++c) w8[c] = (bf16)(acc[c] * rs);
#pragma unroll
        for (int c = 0; c < 8; ++c) w2[c] = (bf16)(acc2[c] * rs * post2);
        *(bf16x8*)(outH + (size_t)r * 256 + lc * 16) = w8;
        *(bf16x8*)(outH2 + (size_t)r * D + lc * 8) = w2;
        if (lc == 0) rowfac[r] = sd * rs;
    }
}

extern "C" void kernel_launch(void* const* d_in, const int* in_sizes, int n_in,
                              void* d_out, int out_size, void* d_ws, size_t ws_size,
                              hipStream_t stream) {
    const float* vfeat  = (const float*)d_in[0];
    const float* efeat  = (const float*)d_in[1];
    const float* invDV  = (const float*)d_in[2];
    const float* invDE  = (const float*)d_in[3];
    const int*   inc_v  = (const int*)d_in[4];
    const int*   inc_e  = (const int*)d_in[5];
    const int*   eM_row = (const int*)d_in[6];
    const int*   eM_col = (const int*)d_in[7];
    const float* eM_val = (const float*)d_in[8];
    const int*   vM_row = (const int*)d_in[9];
    const int*   vM_col = (const int*)d_in[10];
    const float* vM_val = (const float*)d_in[11];
    const float* W_psi1 = (const float*)d_in[12];
    const float* b_psi1 = (const float*)d_in[13];
    const float* W_psi2 = (const float*)d_in[14];
    const float* b_psi2 = (const float*)d_in[15];
    const float* W_v    = (const float*)d_in[16];
    const float* W_e    = (const float*)d_in[17];

    const int N = in_sizes[0] / D;
    const int M = in_sizes[1] / D;
    const int E = in_sizes[4];
    const int nnzE = in_sizes[6];
    const int nnzV = in_sizes[9];
    const int TH = 2 * E + nnzE + nnzV;

    float* out = (float*)d_out;
    float* vfeat_new = out;                     // N*D
    float* efeat_new = out + (size_t)N * D;     // M*D

    const int T = 2 * M + 2 * N + 4;

    // fp8 storage scales (keep values in e4m3 sweet range)
    const float S_B = 16.0f;   // vf2preW
    const float S_C = 64.0f;   // vf2W
    const float S_N = 8.0f;    // vnew
    const float S_W = 8.0f;    // efW_e
    const float S_A = 16.0f;   // A'

    // bucket geometry
    const int shE = 8, shV = 10, shEr = 9, shVr = 10;
    auto cdiv = [](int a, int b) { return (a + b - 1) / b; };
    const int nbE  = cdiv(M, 1 << shE);
    const int nbV  = cdiv(N, 1 << shV);
    const int nbEr = cdiv(M, 1 << shEr);
    const int nbVr = cdiv(N, 1 << shVr);
    const int NB = nbE + nbV + nbEr + nbVr;   // 315 (<=1024 required)
    const int4 rbb   = { 0, nbE, nbE + nbV, nbE + nbV + nbEr };
    const int4 SHv   = { shE, shV, shEr, shVr };
    const int4 Kkeys = { M, N, M, N };
    const int bV  = M + 1;
    const int bEr = bV + (N + 1);
    const int bVr = bEr + (M + 1);
    const int4 rbOff = { 0, bV, bEr, bVr };

    // workspace layout (8B-aligned large arrays first)
    unsigned char* nP8 = (unsigned char*)d_ws;          // N*256B  [vfeat8 | vf2W8->vnew8]
    unsigned char* nB8 = nP8 + (size_t)N * 256;         // N*128B  vf2preW8 (x16)
    bf16* mE  = (bf16*)(nB8 + (size_t)N * 128);         // M*D  efeatH
    unsigned char* mWe8 = (unsigned char*)(mE + (size_t)M * D);  // M*128B efW_e8 -> A'8
    bf16* mV  = (bf16*)(mWe8 + (size_t)M * 128);        // M*D  efW_v
    bf16* mB  = mV + (size_t)M * D;                     // M*D  _efeatV
    bf16* mC  = mB + (size_t)M * D;                     // M*D  ef3preW
    bf16* mP  = mC + (size_t)M * D;                     // M*D  psi gather out (1 then 2)
    unsigned char* mA8 = mWe8;                          // alias: A'8 after efW_e8 dead
    float* W1f = (float*)(mP + (size_t)M * D);          // 128*256
    float* W2f = W1f + 128 * 256;                       // 128*256
    float* b1f = W2f + 128 * 256;                       // 128
    float* b2f = b1f + 128;                             // 128
    float* rowfac = b2f + 128;                          // M  (M*4 divisible by 8)
    uint2* sl_all = (uint2*)(rowfac + M);               // TH packed (gs,w)
    uint2* stg    = sl_all + TH;                        // NB*BCAP packed staging
    int* off_all  = (int*)(stg + (size_t)NB * BCAP);    // T
    int* bcur     = off_all + T;                        // NB (memset)

    int* offE  = off_all;
    int* offV  = off_all + bV;
    int* offEr = off_all + bEr;
    int* offVr = off_all + bVr;

    const dim3 TB(256);

    // ---- CSR build: bucketed append (fixed cap) -> per-bucket finalize (self-scan) ----
    hipMemsetAsync(bcur, 0, (size_t)NB * 4, stream);
    bucket_pass<<<cdiv(TH, BTILE), TB, 0, stream>>>(
        inc_e, inc_v, eM_row, eM_col, eM_val, vM_row, vM_col, vM_val,
        invDV, invDE, E, nnzE, nnzV, rbb, SHv, NB, bcur, stg);
    finalize_pass<<<NB, TB, 0, stream>>>(
        rbOff, rbb, SHv, Kkeys, NB, bcur, stg, off_all, sl_all);

    // ---- fused prep: fp8(vfeat), bf16(efeat), weight folds ----
    const int nb8 = cdiv(N * D / 8, 256), nb16 = cdiv(M * D / 4, 256);
    prep_all<<<nb8 + nb16 + 257, TB, 0, stream>>>(
        vfeat, N * D / 8, nP8, 256, efeat, M * D / 4, mE,
        W_v, W_psi1, b_psi1, W_e, W_psi2, b_psi2,
        W1f, b1f, W2f, b2f, nb8, nb16);

    // ---- pipeline (Wv/We-transformed space; fp8 on attenuated paths) ----
    // efW_e8 = fp8(efeat @ W_e^T * 8) ; efW_v = bf16(efeat @ W_v^T)
    gemm_dual<<<cdiv(M, 128), TB, 0, stream>>>(mE, W_e, W_v, mWe8, S_W, mV, M);
    // vf2preW8 = fp8(mean_v(efW_e[inc_e]*invDE) * 16)   [w packed in sl]
    seg_gather<1, 1, 0, 1><<<cdiv(N, 16), TB, 0, stream>>>(
        mWe8, 128, 0, nullptr, 0, 0, offV, sl_all, nullptr,
        nB8, 128, 0, nullptr, nullptr, nullptr, 1.0f / S_W, 1.0f, S_B, N);
    // vf2W8 = fp8(spmm_V(vf2preW) * 64) -> nP8[+128]
    seg_gather<0, 1, 0, 1><<<cdiv(N, 16), TB, 0, stream>>>(
        nB8, 128, 0, nullptr, 0, 0, offVr, sl_all, nullptr,
        nP8, 256, 128, nullptr, nullptr, nullptr, 1.0f / S_B, 1.0f, S_C, N);
    // FUSED psi1: mP = mean_w(vfeat8*dv); mC = ef3preW = mean(vf2W)/64; rowfac = sd/cnt
    seg_gather<7, 1, 1, 0><<<cdiv(M, 16), TB, 0, stream>>>(
        nP8, 256, 0, nP8, 256, 128, offE, sl_all, nullptr,
        (unsigned char*)mP, 256, 0, mC, nullptr, rowfac, 1.0f, 1.0f / S_C, 1.0f, M);
    // A'8 = fp8(([mP ; mE*fac] @ W1f^T + fac*b1f) * 16) -> mA8 (aliases mWe8)
    gemm_psi<<<cdiv(M, 128), TB, 0, stream>>>(
        mP, mE, rowfac, W1f, b1f, nullptr, nullptr, mA8, S_A, M, 0);
    // _efeatV = spmm_E(A')/16 + efW_v -> mB (bf16; feeds outputs, stays bf16)
    seg_gather<0, 1, 0, 0><<<cdiv(M, 16), TB, 0, stream>>>(
        mA8, 128, 0, nullptr, 0, 0, offEr, sl_all, mV,
        (unsigned char*)mB, 256, 0, nullptr, nullptr, nullptr, 1.0f / S_A, 1.0f, 1.0f, M);
    // vfeat_new = relu(mean_v(_efeatV)) -> d_out f32 + vnew8 (nP8[+128], x8; vf2W dead)
    seg_gather<2, 0, 0, 1><<<cdiv(N, 16), TB, 0, stream>>>(
        (unsigned char*)mB, 256, 0, nullptr, 0, 0, offV, sl_all, nullptr,
        nP8, 256, 128, nullptr, vfeat_new, nullptr, 1.0f, 1.0f, S_N, N);
    // psi2: mP = mean(vnew8)/8; rowfac = [cnt>0]
    seg_gather<6, 1, 0, 0><<<cdiv(M, 16), TB, 0, stream>>>(
        nP8, 256, 128, nullptr, 0, 0, offE, sl_all, nullptr,
        (unsigned char*)mP, 256, 0, nullptr, nullptr, rowfac, 1.0f / S_N, 1.0f, 1.0f, M);
    // efeat_new = relu([mP ; mE*fac] @ W2f^T + fac*b2f + ef3preW) -> d_out
    gemm_psi<<<cdiv(M, 128), TB, 0, stream>>>(
        mP, mE, rowfac, W2f, b2f, mC, efeat_new, nullptr, 1.0f, M, 1);
}